// Round 20
// baseline (523.351 us; speedup 1.0000x reference)
//
#include <hip/hip_runtime.h>
#include <stdint.h>
#include <stddef.h>

typedef short bf16x8 __attribute__((ext_vector_type(8)));
typedef unsigned short ushort8 __attribute__((ext_vector_type(8)));
typedef unsigned short usv4 __attribute__((ext_vector_type(4)));
typedef float f32x4 __attribute__((ext_vector_type(4)));

__device__ __forceinline__ unsigned short f2bf(float f) {
  union { float f; unsigned int u; } v; v.f = f;
  unsigned int r = v.u + 0x7FFFu + ((v.u >> 16) & 1u);  // RNE
  return (unsigned short)(r >> 16);
}
__device__ __forceinline__ float bf2f(unsigned short u) {
  union { unsigned int u; float f; } v; v.u = ((unsigned int)u) << 16; return v.f;
}
// raw barrier WITHOUT vmcnt(0) drain (LDS coherence only; globals stay in flight)
__device__ __forceinline__ void barrier_nodrain() {
  asm volatile("s_waitcnt lgkmcnt(0)" ::: "memory");
  __builtin_amdgcn_sched_barrier(0);
  __builtin_amdgcn_s_barrier();
  __builtin_amdgcn_sched_barrier(0);
}

#define PAD 96

// ---------------- prep: B-fragments + biases + zero(cnt/stats) ----------------
__global__ void prep_frag(
    const float* __restrict__ Wsh, const float* __restrict__ Whu, const float* __restrict__ Wmo,
    const float* __restrict__ Wn1, const float* __restrict__ Wn2,
    const float* __restrict__ Wlin, const float* __restrict__ Wd1,
    unsigned short* __restrict__ WCf, unsigned short* __restrict__ WN1f,
    unsigned short* __restrict__ WN2f, unsigned short* __restrict__ WHf,
    const float* __restrict__ bsh, const float* __restrict__ bhu, const float* __restrict__ bmo,
    const float* __restrict__ blin, const float* __restrict__ bd1,
    float* __restrict__ b3, float* __restrict__ bhead,
    int* __restrict__ zeroRegion, int zeroCount)
{
  const int NB_FRAG = 6784;   // 106*16384/256
  const int bid = blockIdx.x;
  const int tid = threadIdx.x;
  if (bid < NB_FRAG) {
    const int s0 = 64 * 16384, s1 = s0 + 14 * 16384, s2 = s1 + 14 * 16384;
    int idx = bid * 256 + tid;
    int mode, rel;
    unsigned short* out;
    if (idx < s0)      { mode = 0; rel = idx;      out = WCf;  }
    else if (idx < s1) { mode = 1; rel = idx - s0; out = WN1f; }
    else if (idx < s2) { mode = 3; rel = idx - s1; out = WN2f; }
    else               { mode = 2; rel = idx - s2; out = WHf;  }
    int t = rel >> 14;
    int rem = rel & 16383;
    int e = rem & 7;
    int chunk = rem >> 3;
    int lane = chunk & 63;
    int g = chunk >> 6;
    int col = g * 16 + (lane & 15);
    int k = t * 32 + ((lane >> 4) << 3) + e;
    float v = 0.f;
    if (mode == 0) {
      if (col < 400 && k < 2000) {
        if (k < 1000)      v = Wsh[col * 1000 + k];
        else if (k < 1500) v = Whu[col * 500 + (k - 1000)];
        else               v = Wmo[col * 500 + (k - 1500)];
      }
    } else if (mode == 1) {
      if (col < 400 && k < 400) v = Wn1[col * 400 + k];
    } else if (mode == 3) {
      if (col < 400 && k < 400) v = Wn2[col * 400 + k];
    } else {
      if (k < 400) {
        if (col < 20)      v = Wlin[col * 400 + k];
        else if (col < 70) v = Wd1[(col - 20) * 400 + k];
      }
    }
    out[rel] = f2bf(v);
  } else if (bid == NB_FRAG) {
    for (int t = tid; t < 512; t += 256) {
      if (t < 416) b3[t] = (t < 400) ? (bsh[t] + bhu[t] + bmo[t]) : 0.f;
      bhead[t] = (t < 20) ? blin[t] : ((t < 70) ? bd1[t - 20] : 0.f);
    }
  } else {
    for (int i = tid; i < zeroCount; i += 256) zeroRegion[i] = 0;
  }
}

// ---------------- stage-1 GEMM (938 blocks, 512 thr = 8 waves, wave 64x64) + adjacency ----------------
// B DOUBLE-BUFFERED (bbA even steps / bbB odd steps — each gets a full K-step of latency
// cover). ~144 unified regs -> launch_bounds(512,3) = 3 waves/SIMD (no spill).
// A: LDS dbuf [2][64][36] bf16, one f32x4/thread/step, 2-step named-set prefetch.
// Raw nodrain barriers. Blocks >= NGEMM: padded-adjacency scatter.
__global__ __launch_bounds__(512, 3) void gemm_stage1_adj(
    const float* __restrict__ Af, const unsigned short* __restrict__ Bf,
    const float* __restrict__ bias, unsigned short* __restrict__ C,
    int M, int Kreal, int ksteps, int NGEMM,
    const int* __restrict__ dst1, const int* __restrict__ src1, const int* __restrict__ eid1,
    int* __restrict__ cnt1, int* __restrict__ esrcP1, float* __restrict__ ewP1, int E1,
    const int* __restrict__ dst2, const int* __restrict__ src2, const int* __restrict__ eid2,
    int* __restrict__ cnt2, int* __restrict__ esrcP2, float* __restrict__ ewP2, int E2,
    const float* __restrict__ wall)
{
  __shared__ unsigned short As[2][64][36];

  if (blockIdx.x >= NGEMM) {
    int e = (blockIdx.x - NGEMM) * 512 + threadIdx.x;
    if (e < E1) {
      int d = dst1[e];
      int pos = atomicAdd(&cnt1[d], 1);
      if (pos < PAD) {
        esrcP1[d * PAD + pos] = src1[e];
        ewP1[d * PAD + pos] = wall[eid1[e]];
      }
    } else if (e < E1 + E2) {
      int e2 = e - E1;
      int d = dst2[e2];
      int pos = atomicAdd(&cnt2[d], 1);
      if (pos < PAD) {
        esrcP2[d * PAD + pos] = src2[e2];
        ewP2[d * PAD + pos] = wall[eid2[e2]];
      }
    }
    return;
  }

  const int tid = threadIdx.x;
  const int lane = tid & 63;
  const int wv = tid >> 6;            // 0..7
  const int rowBase = blockIdx.x * 64;
  const int sRow = tid >> 3;          // 0..63
  const int sC = (tid & 7) << 2;      // 0,4,...,28
  const int aRow = rowBase + sRow;
  const bool aOK = aRow < M;
  const int fr = lane & 15;
  const int fq = lane >> 4;

  const unsigned short* bWave = Bf + ((size_t)(wv * 4) * 64 + lane) * 8;

  f32x4 acc[4][4] = {};
  f32x4 a0, a1;                   // named A staging sets
  bf16x8 bbA[4], bbB[4];          // B double buffer (even / odd steps)

  auto loadBA = [&](int t) {
    const unsigned short* bp = bWave + (size_t)t * 16384;
    #pragma unroll
    for (int ni = 0; ni < 4; ++ni) bbA[ni] = *(const bf16x8*)(bp + ni * 512);
  };
  auto loadBB = [&](int t) {
    const unsigned short* bp = bWave + (size_t)t * 16384;
    #pragma unroll
    for (int ni = 0; ni < 4; ++ni) bbB[ni] = *(const bf16x8*)(bp + ni * 512);
  };
  auto loadA0 = [&](int t) {
    const int k0 = t * 32 + sC;
    if (aOK && (k0 + 4) <= Kreal) a0 = *(const f32x4*)(Af + (size_t)aRow * Kreal + k0);
    else { a0[0]=0.f; a0[1]=0.f; a0[2]=0.f; a0[3]=0.f; }
  };
  auto loadA1 = [&](int t) {
    const int k0 = t * 32 + sC;
    if (aOK && (k0 + 4) <= Kreal) a1 = *(const f32x4*)(Af + (size_t)aRow * Kreal + k0);
    else { a1[0]=0.f; a1[1]=0.f; a1[2]=0.f; a1[3]=0.f; }
  };
  auto writeA0 = [&](int buf) {
    usv4 w;
    w[0]=f2bf(a0[0]); w[1]=f2bf(a0[1]); w[2]=f2bf(a0[2]); w[3]=f2bf(a0[3]);
    *(usv4*)&As[buf][sRow][sC] = w;
  };
  auto writeA1 = [&](int buf) {
    usv4 w;
    w[0]=f2bf(a1[0]); w[1]=f2bf(a1[1]); w[2]=f2bf(a1[2]); w[3]=f2bf(a1[3]);
    *(usv4*)&As[buf][sRow][sC] = w;
  };
  auto computeA = [&](int buf) {
    bf16x8 af[4];
    #pragma unroll
    for (int mi = 0; mi < 4; ++mi)
      af[mi] = *(const bf16x8*)&As[buf][(mi << 4) + fr][fq << 3];
    #pragma unroll
    for (int ni = 0; ni < 4; ++ni)
      #pragma unroll
      for (int mi = 0; mi < 4; ++mi)
        acc[mi][ni] = __builtin_amdgcn_mfma_f32_16x16x32_bf16(af[mi], bbA[ni], acc[mi][ni], 0, 0, 0);
  };
  auto computeB = [&](int buf) {
    bf16x8 af[4];
    #pragma unroll
    for (int mi = 0; mi < 4; ++mi)
      af[mi] = *(const bf16x8*)&As[buf][(mi << 4) + fr][fq << 3];
    #pragma unroll
    for (int ni = 0; ni < 4; ++ni)
      #pragma unroll
      for (int mi = 0; mi < 4; ++mi)
        acc[mi][ni] = __builtin_amdgcn_mfma_f32_16x16x32_bf16(af[mi], bbB[ni], acc[mi][ni], 0, 0, 0);
  };

  const int ksm1 = ksteps - 1;
  loadA0(0);
  loadBA(0);
  loadA1(1 < ksm1 ? 1 : ksm1);
  loadBB(1 < ksm1 ? 1 : ksm1);
  writeA0(0);
  barrier_nodrain();
  loadA0(2 < ksm1 ? 2 : ksm1);

  for (int t = 0; t + 1 < ksteps; t += 2) {
    // step t (even): As[0], bbA = B(t)
    computeA(0);
    loadBA(t + 2 < ksm1 ? t + 2 : ksm1);   // full step of cover before next use
    writeA1(1);
    barrier_nodrain();
    loadA1(t + 3 < ksm1 ? t + 3 : ksm1);
    // step t+1 (odd): As[1], bbB = B(t+1)
    computeB(1);
    loadBB(t + 3 < ksm1 ? t + 3 : ksm1);
    writeA0(0);
    barrier_nodrain();
    loadA0(t + 4 < ksm1 ? t + 4 : ksm1);
  }
  computeA(0);   // tail step ksm1 (even): bbA = B(ksm1) loaded at t = ksm1-2

  #pragma unroll
  for (int mi = 0; mi < 4; ++mi) {
    const int row0 = rowBase + (mi << 4) + (fq << 2);
    #pragma unroll
    for (int ni = 0; ni < 4; ++ni) {
      const int col = (wv << 6) + (ni << 4) + fr;
      if (col < 416) {
        const float bv = (col < 400) ? bias[col] : 0.f;
        #pragma unroll
        for (int r = 0; r < 4; ++r) {
          const int row = row0 + r;
          if (row < M) C[(size_t)row * 416 + col] =
              (col < 400) ? f2bf(acc[mi][ni][r] + bv) : (unsigned short)0;
        }
      }
    }
  }
}

// ---------------- fused GNN layer: gather (padded adj) -> LDS -> GEMM (-> head + bn) ----------------
template<int HEAD, int ROWS>
__global__ __launch_bounds__(512) void fused_layer(
    const unsigned short* __restrict__ hsrc, const int* __restrict__ deg,
    const int* __restrict__ esrcP, const float* __restrict__ ewP,
    const unsigned short* __restrict__ Bf, const float* __restrict__ bias,
    unsigned short* __restrict__ Cout,
    const unsigned short* __restrict__ BfH, const float* __restrict__ biasH,
    float* __restrict__ outHx, float* __restrict__ dRaw, float* __restrict__ stats, int nDst)
{
  constexpr int MI = ROWS / 16;
  constexpr int NPW = ROWS / 8;        // nodes per wave
  __shared__ unsigned short T[ROWS][456];
  const int tid = threadIdx.x;
  const int lane = tid & 63;
  const int wv = tid >> 6;
  const int rowBase = blockIdx.x * ROWS;
  const int fr = lane & 15;
  const int fq = lane >> 4;

  for (int i = 0; i < NPW; ++i) {
    const int row = wv * NPW + i;
    const int node = rowBase + row;
    if (lane < 52) {
      float a[8];
      if (node < nDst) {
        ushort8 v = *(const ushort8*)(hsrc + (size_t)node * 416 + lane * 8);
        #pragma unroll
        for (int j = 0; j < 8; ++j) a[j] = bf2f(v[j]);
        int dg = deg[node]; if (dg > PAD) dg = PAD;
        const int e0 = node * PAD, e1 = e0 + dg;
        int e = e0;
        for (; e + 16 <= e1; e += 16) {
          int ss[16]; float ww[16];
          #pragma unroll
          for (int u = 0; u < 16; ++u) { ss[u] = esrcP[e + u]; ww[u] = ewP[e + u]; }
          ushort8 q0  = *(const ushort8*)(hsrc + (size_t)ss[0]  * 416 + lane * 8);
          ushort8 q1  = *(const ushort8*)(hsrc + (size_t)ss[1]  * 416 + lane * 8);
          ushort8 q2  = *(const ushort8*)(hsrc + (size_t)ss[2]  * 416 + lane * 8);
          ushort8 q3  = *(const ushort8*)(hsrc + (size_t)ss[3]  * 416 + lane * 8);
          ushort8 q4  = *(const ushort8*)(hsrc + (size_t)ss[4]  * 416 + lane * 8);
          ushort8 q5  = *(const ushort8*)(hsrc + (size_t)ss[5]  * 416 + lane * 8);
          ushort8 q6  = *(const ushort8*)(hsrc + (size_t)ss[6]  * 416 + lane * 8);
          ushort8 q7  = *(const ushort8*)(hsrc + (size_t)ss[7]  * 416 + lane * 8);
          ushort8 q8  = *(const ushort8*)(hsrc + (size_t)ss[8]  * 416 + lane * 8);
          ushort8 q9  = *(const ushort8*)(hsrc + (size_t)ss[9]  * 416 + lane * 8);
          ushort8 q10 = *(const ushort8*)(hsrc + (size_t)ss[10] * 416 + lane * 8);
          ushort8 q11 = *(const ushort8*)(hsrc + (size_t)ss[11] * 416 + lane * 8);
          ushort8 q12 = *(const ushort8*)(hsrc + (size_t)ss[12] * 416 + lane * 8);
          ushort8 q13 = *(const ushort8*)(hsrc + (size_t)ss[13] * 416 + lane * 8);
          ushort8 q14 = *(const ushort8*)(hsrc + (size_t)ss[14] * 416 + lane * 8);
          ushort8 q15 = *(const ushort8*)(hsrc + (size_t)ss[15] * 416 + lane * 8);
          #pragma unroll
          for (int j = 0; j < 8; ++j) {
            float p0 = (bf2f(q0[j])*ww[0] + bf2f(q1[j])*ww[1]) + (bf2f(q2[j])*ww[2] + bf2f(q3[j])*ww[3]);
            float p1 = (bf2f(q4[j])*ww[4] + bf2f(q5[j])*ww[5]) + (bf2f(q6[j])*ww[6] + bf2f(q7[j])*ww[7]);
            float p2 = (bf2f(q8[j])*ww[8] + bf2f(q9[j])*ww[9]) + (bf2f(q10[j])*ww[10] + bf2f(q11[j])*ww[11]);
            float p3 = (bf2f(q12[j])*ww[12] + bf2f(q13[j])*ww[13]) + (bf2f(q14[j])*ww[14] + bf2f(q15[j])*ww[15]);
            a[j] += (p0 + p1) + (p2 + p3);
          }
        }
        for (; e + 4 <= e1; e += 4) {
          const int s0 = esrcP[e], s1 = esrcP[e+1], s2 = esrcP[e+2], s3 = esrcP[e+3];
          const float w0 = ewP[e], w1 = ewP[e+1], w2 = ewP[e+2], w3 = ewP[e+3];
          ushort8 q0 = *(const ushort8*)(hsrc + (size_t)s0 * 416 + lane * 8);
          ushort8 q1 = *(const ushort8*)(hsrc + (size_t)s1 * 416 + lane * 8);
          ushort8 q2 = *(const ushort8*)(hsrc + (size_t)s2 * 416 + lane * 8);
          ushort8 q3 = *(const ushort8*)(hsrc + (size_t)s3 * 416 + lane * 8);
          #pragma unroll
          for (int j = 0; j < 8; ++j)
            a[j] += (bf2f(q0[j]) * w0 + bf2f(q1[j]) * w1) + (bf2f(q2[j]) * w2 + bf2f(q3[j]) * w3);
        }
        for (; e < e1; ++e) {
          const int s = esrcP[e];
          const float w = ewP[e];
          ushort8 q = *(const ushort8*)(hsrc + (size_t)s * 416 + lane * 8);
          #pragma unroll
          for (int j = 0; j < 8; ++j) a[j] += bf2f(q[j]) * w;
        }
        const float inv = 1.f / ((float)dg + 1.f);
        ushort8 o;
        #pragma unroll
        for (int j = 0; j < 8; ++j) o[j] = f2bf(a[j] * inv);
        *(ushort8*)&T[row][lane * 8] = o;
      } else {
        ushort8 o;
        #pragma unroll
        for (int j = 0; j < 8; ++j) o[j] = 0;
        *(ushort8*)&T[row][lane * 8] = o;
      }
    } else if (lane < 57) {
      ushort8 o;
      #pragma unroll
      for (int j = 0; j < 8; ++j) o[j] = 0;
      *(ushort8*)&T[row][416 + (lane - 52) * 8] = o;
    }
  }
  __syncthreads();

  const unsigned short* bWave = Bf + ((size_t)(wv * 4) * 64 + lane) * 8;
  f32x4 acc[MI][4] = {};
  bf16x8 bbA[4], bbB[4];

  auto loadBA = [&](int kh) {
    const unsigned short* bp = bWave + (size_t)kh * 16384;
    #pragma unroll
    for (int ni = 0; ni < 4; ++ni) bbA[ni] = *(const bf16x8*)(bp + ni * 512);
  };
  auto loadBB = [&](int kh) {
    const unsigned short* bp = bWave + (size_t)kh * 16384;
    #pragma unroll
    for (int ni = 0; ni < 4; ++ni) bbB[ni] = *(const bf16x8*)(bp + ni * 512);
  };
  auto computeA2 = [&](int kh) {
    bf16x8 af[MI];
    #pragma unroll
    for (int mi = 0; mi < MI; ++mi)
      af[mi] = *(const bf16x8*)&T[(mi << 4) + fr][kh * 32 + (fq << 3)];
    #pragma unroll
    for (int ni = 0; ni < 4; ++ni)
      #pragma unroll
      for (int mi = 0; mi < MI; ++mi)
        acc[mi][ni] = __builtin_amdgcn_mfma_f32_16x16x32_bf16(af[mi], bbA[ni], acc[mi][ni], 0, 0, 0);
  };
  auto computeB2 = [&](int kh) {
    bf16x8 af[MI];
    #pragma unroll
    for (int mi = 0; mi < MI; ++mi)
      af[mi] = *(const bf16x8*)&T[(mi << 4) + fr][kh * 32 + (fq << 3)];
    #pragma unroll
    for (int ni = 0; ni < 4; ++ni)
      #pragma unroll
      for (int mi = 0; mi < MI; ++mi)
        acc[mi][ni] = __builtin_amdgcn_mfma_f32_16x16x32_bf16(af[mi], bbB[ni], acc[mi][ni], 0, 0, 0);
  };

  loadBA(0);
  loadBB(1);
  for (int kh = 0; kh + 1 < 14; kh += 2) {
    computeA2(kh);
    loadBA(kh + 2 < 13 ? kh + 2 : 13);
    computeB2(kh + 1);
    loadBB(kh + 3 < 13 ? kh + 3 : 13);
  }

  if (HEAD == 0) {
    #pragma unroll
    for (int mi = 0; mi < MI; ++mi) {
      const int row0 = rowBase + (mi << 4) + (fq << 2);
      #pragma unroll
      for (int ni = 0; ni < 4; ++ni) {
        const int col = (wv << 6) + (ni << 4) + fr;
        if (col < 416) {
          const float bv = (col < 400) ? bias[col] : 0.f;
          #pragma unroll
          for (int r = 0; r < 4; ++r) {
            const int row = row0 + r;
            if (row < nDst) Cout[(size_t)row * 416 + col] =
                (col < 400) ? f2bf(acc[mi][ni][r] + bv) : (unsigned short)0;
          }
        }
      }
    }
  } else {
    __syncthreads();
    #pragma unroll
    for (int mi = 0; mi < MI; ++mi) {
      const int lrow0 = (mi << 4) + (fq << 2);
      #pragma unroll
      for (int ni = 0; ni < 4; ++ni) {
        const int col = (wv << 6) + (ni << 4) + fr;
        if (col < 456) {
          const float bv = (col < 400) ? bias[col] : 0.f;
          #pragma unroll
          for (int r = 0; r < 4; ++r)
            T[lrow0 + r][col] = (col < 400) ? f2bf(acc[mi][ni][r] + bv) : (unsigned short)0;
        }
      }
    }
    __syncthreads();
    const unsigned short* bhWave = BfH + ((size_t)wv * 64 + lane) * 8;
    f32x4 acc2[MI] = {};
    bf16x8 bhA, bhB;
    auto loadHA = [&](int kh) { bhA = *(const bf16x8*)(bhWave + (size_t)kh * 16384); };
    auto loadHB = [&](int kh) { bhB = *(const bf16x8*)(bhWave + (size_t)kh * 16384); };
    auto computeHA = [&](int kh) {
      #pragma unroll
      for (int mi = 0; mi < MI; ++mi) {
        bf16x8 af = *(const bf16x8*)&T[(mi << 4) + fr][kh * 32 + (fq << 3)];
        acc2[mi] = __builtin_amdgcn_mfma_f32_16x16x32_bf16(af, bhA, acc2[mi], 0, 0, 0);
      }
    };
    auto computeHB = [&](int kh) {
      #pragma unroll
      for (int mi = 0; mi < MI; ++mi) {
        bf16x8 af = *(const bf16x8*)&T[(mi << 4) + fr][kh * 32 + (fq << 3)];
        acc2[mi] = __builtin_amdgcn_mfma_f32_16x16x32_bf16(af, bhB, acc2[mi], 0, 0, 0);
      }
    };
    loadHA(0);
    loadHB(1);
    for (int kh = 0; kh + 1 < 14; kh += 2) {
      computeHA(kh);
      loadHA(kh + 2 < 13 ? kh + 2 : 13);
      computeHB(kh + 1);
      loadHB(kh + 3 < 13 ? kh + 3 : 13);
    }
    const int col = (wv << 4) + fr;
    const bool colOK = (col < 70);
    const float bv = colOK ? biasH[col] : 0.f;
    if (colOK) {
      #pragma unroll
      for (int mi = 0; mi < MI; ++mi) {
        const int row0 = rowBase + (mi << 4) + (fq << 2);
        #pragma unroll
        for (int r = 0; r < 4; ++r) {
          const int row = row0 + r;
          if (row < nDst) {
            float v = acc2[mi][r] + bv;
            if (col < 20) outHx[(size_t)row * 20 + col] = v;
            else          dRaw[(size_t)row * 50 + (col - 20)] = v;
          }
        }
      }
    }
    float s = 0.f, s2 = 0.f;
    if (col >= 20 && col < 70) {
      #pragma unroll
      for (int mi = 0; mi < MI; ++mi) {
        const int row0 = rowBase + (mi << 4) + (fq << 2);
        #pragma unroll
        for (int r = 0; r < 4; ++r) {
          if (row0 + r < nDst) {
            float v = acc2[mi][r] + bv;
            s += v; s2 += v * v;
          }
        }
      }
    }
    s  += __shfl_xor(s, 16);  s  += __shfl_xor(s, 32);
    s2 += __shfl_xor(s2, 16); s2 += __shfl_xor(s2, 32);
    if (col >= 20 && col < 70 && fq == 0) {
      atomicAdd(&stats[col - 20], s);
      atomicAdd(&stats[50 + col - 20], s2);
    }
  }
}

// ---------------- bn finalize + domain head ----------------
__global__ void domain_head2(const float* __restrict__ d, const float* __restrict__ stats,
                             const float* __restrict__ gamma, const float* __restrict__ beta,
                             const float* __restrict__ Wd2, const float* __restrict__ bd2,
                             float* __restrict__ out, int rows)
{
  __shared__ float ss[100];
  const int t = threadIdx.x;
  if (t < 50) {
    float mu = stats[t] / rows;
    float var = stats[50 + t] / rows - mu * mu;
    float inv = rsqrtf(var + 1e-5f);
    float sc = gamma[t] * inv;
    ss[t] = sc;
    ss[50 + t] = beta[t] - mu * sc;
  }
  __syncthreads();
  int r = blockIdx.x * 256 + t;
  if (r >= rows) return;
  float o0 = bd2[0], o1 = bd2[1];
  const float* dr = d + (size_t)r * 50;
  #pragma unroll 10
  for (int c = 0; c < 50; ++c) {
    float v = dr[c] * ss[c] + ss[50 + c];
    v = fmaxf(v, 0.f);
    o0 += v * Wd2[c];
    o1 += v * Wd2[50 + c];
  }
  out[r * 2]     = o0;
  out[r * 2 + 1] = o1;
}

// ---------------- launch ----------------
extern "C" void kernel_launch(void* const* d_in, const int* in_sizes, int n_in,
                              void* d_out, int out_size, void* d_ws, size_t ws_size,
                              hipStream_t stream)
{
  const float* x    = (const float*)d_in[0];
  const float* wall = (const float*)d_in[1];
  const float* Wsh  = (const float*)d_in[2];
  const float* bsh  = (const float*)d_in[3];
  const float* Whu  = (const float*)d_in[4];
  const float* bhu  = (const float*)d_in[5];
  const float* Wmo  = (const float*)d_in[6];
  const float* bmo  = (const float*)d_in[7];
  const float* Wn1  = (const float*)d_in[8];
  const float* bn1  = (const float*)d_in[9];
  const float* Wn2  = (const float*)d_in[10];
  const float* bn2  = (const float*)d_in[11];
  const float* Wlin = (const float*)d_in[12];
  const float* blin = (const float*)d_in[13];
  const float* Wd1  = (const float*)d_in[14];
  const float* bd1  = (const float*)d_in[15];
  const float* gamma= (const float*)d_in[16];
  const float* beta = (const float*)d_in[17];
  const float* Wd2  = (const float*)d_in[18];
  const float* bd2  = (const float*)d_in[19];
  const int* src1 = (const int*)d_in[20];
  const int* dst1 = (const int*)d_in[21];
  const int* eid1 = (const int*)d_in[22];
  const int* src2 = (const int*)d_in[23];
  const int* dst2 = (const int*)d_in[24];
  const int* eid2 = (const int*)d_in[25];

  char* ws = (char*)d_ws;
  unsigned short* h    = (unsigned short*)(ws);                    // [60000][416] bf16
  unsigned short* h1   = (unsigned short*)(ws + 49920000ULL);      // [30000][416]
  float* d_raw         = (float*)(ws + 74880000ULL);               // [15000][50] f32
  unsigned short* WCf  = (unsigned short*)(ws + 77880000ULL);      // 64*16384 ushorts
  unsigned short* WN1f = (unsigned short*)(ws + 79977152ULL);      // 14*16384
  unsigned short* WN2f = (unsigned short*)(ws + 80435904ULL);
  unsigned short* WHf  = (unsigned short*)(ws + 80894656ULL);
  float* b3      = (float*)(ws + 81353408ULL);
  float* bhead   = (float*)(ws + 81355456ULL);
  // contiguous zero region: cnt1, cnt2, stats (45100 ints)
  int*   cnt1    = (int*)(ws + 81357504ULL);                       // 120000 B
  int*   cnt2    = (int*)(ws + 81477504ULL);                       // 60000 B
  float* stats   = (float*)(ws + 81537504ULL);                     // 400 B
  int*   esrcP1  = (int*)(ws + 81538304ULL);                       // 11520000 B
  float* ewP1    = (float*)(ws + 93058304ULL);                     // 11520000 B
  int*   esrcP2  = (int*)(ws + 104578304ULL);                      // 5760000 B
  float* ewP2    = (float*)(ws + 110338304ULL);                    // 5760000 B

  const int E1 = 960000, E2 = 480000;
  const int N0 = 60000, N1 = 30000, N2 = 15000;

  prep_frag<<<6786, 256, 0, stream>>>(
      Wsh, Whu, Wmo, Wn1, Wn2, Wlin, Wd1, WCf, WN1f, WN2f, WHf,
      bsh, bhu, bmo, blin, bd1, b3, bhead,
      cnt1, 45100);

  gemm_stage1_adj<<<938 + 2813, 512, 0, stream>>>(
      x, WCf, b3, h, N0, 2000, 63, 938,
      dst1, src1, eid1, cnt1, esrcP1, ewP1, E1,
      dst2, src2, eid2, cnt2, esrcP2, ewP2, E2, wall);

  float* out_hx  = (float*)d_out;            // 15000 x 20
  float* out_dom = (float*)d_out + 300000;   // 15000 x 2

  fused_layer<0, 32><<<(N1 + 31) / 32, 512, 0, stream>>>(
      h, cnt1, esrcP1, ewP1, WN1f, bn1, h1, nullptr, nullptr, nullptr, nullptr, nullptr, N1);

  fused_layer<1, 32><<<(N2 + 31) / 32, 512, 0, stream>>>(
      h1, cnt2, esrcP2, ewP2, WN2f, bn2, nullptr, WHf, bhead, out_hx, d_raw, stats, N2);

  domain_head2<<<(N2 + 255) / 256, 256, 0, stream>>>(d_raw, stats, gamma, beta, Wd2, bd2, out_dom, N2);
}

// Round 21
// 492.103 us; speedup vs baseline: 1.0635x; 1.0635x over previous
//
#include <hip/hip_runtime.h>
#include <stdint.h>
#include <stddef.h>

typedef short bf16x8 __attribute__((ext_vector_type(8)));
typedef unsigned short ushort8 __attribute__((ext_vector_type(8)));
typedef unsigned short usv4 __attribute__((ext_vector_type(4)));
typedef float f32x4 __attribute__((ext_vector_type(4)));

__device__ __forceinline__ unsigned short f2bf(float f) {
  union { float f; unsigned int u; } v; v.f = f;
  unsigned int r = v.u + 0x7FFFu + ((v.u >> 16) & 1u);  // RNE
  return (unsigned short)(r >> 16);
}
__device__ __forceinline__ float bf2f(unsigned short u) {
  union { unsigned int u; float f; } v; v.u = ((unsigned int)u) << 16; return v.f;
}
// raw barrier WITHOUT vmcnt(0) drain (LDS coherence only; globals stay in flight)
__device__ __forceinline__ void barrier_nodrain() {
  asm volatile("s_waitcnt lgkmcnt(0)" ::: "memory");
  __builtin_amdgcn_sched_barrier(0);
  __builtin_amdgcn_s_barrier();
  __builtin_amdgcn_sched_barrier(0);
}

#define PAD 96

// ---------------- prep: B-fragments + biases + zero(cnt/stats) ----------------
__global__ void prep_frag(
    const float* __restrict__ Wsh, const float* __restrict__ Whu, const float* __restrict__ Wmo,
    const float* __restrict__ Wn1, const float* __restrict__ Wn2,
    const float* __restrict__ Wlin, const float* __restrict__ Wd1,
    unsigned short* __restrict__ WCf, unsigned short* __restrict__ WN1f,
    unsigned short* __restrict__ WN2f, unsigned short* __restrict__ WHf,
    const float* __restrict__ bsh, const float* __restrict__ bhu, const float* __restrict__ bmo,
    const float* __restrict__ blin, const float* __restrict__ bd1,
    float* __restrict__ b3, float* __restrict__ bhead,
    int* __restrict__ zeroRegion, int zeroCount)
{
  const int NB_FRAG = 6784;   // 106*16384/256
  const int bid = blockIdx.x;
  const int tid = threadIdx.x;
  if (bid < NB_FRAG) {
    const int s0 = 64 * 16384, s1 = s0 + 14 * 16384, s2 = s1 + 14 * 16384;
    int idx = bid * 256 + tid;
    int mode, rel;
    unsigned short* out;
    if (idx < s0)      { mode = 0; rel = idx;      out = WCf;  }
    else if (idx < s1) { mode = 1; rel = idx - s0; out = WN1f; }
    else if (idx < s2) { mode = 3; rel = idx - s1; out = WN2f; }
    else               { mode = 2; rel = idx - s2; out = WHf;  }
    int t = rel >> 14;
    int rem = rel & 16383;
    int e = rem & 7;
    int chunk = rem >> 3;
    int lane = chunk & 63;
    int g = chunk >> 6;
    int col = g * 16 + (lane & 15);
    int k = t * 32 + ((lane >> 4) << 3) + e;
    float v = 0.f;
    if (mode == 0) {
      if (col < 400 && k < 2000) {
        if (k < 1000)      v = Wsh[col * 1000 + k];
        else if (k < 1500) v = Whu[col * 500 + (k - 1000)];
        else               v = Wmo[col * 500 + (k - 1500)];
      }
    } else if (mode == 1) {
      if (col < 400 && k < 400) v = Wn1[col * 400 + k];
    } else if (mode == 3) {
      if (col < 400 && k < 400) v = Wn2[col * 400 + k];
    } else {
      if (k < 400) {
        if (col < 20)      v = Wlin[col * 400 + k];
        else if (col < 70) v = Wd1[(col - 20) * 400 + k];
      }
    }
    out[rel] = f2bf(v);
  } else if (bid == NB_FRAG) {
    for (int t = tid; t < 512; t += 256) {
      if (t < 416) b3[t] = (t < 400) ? (bsh[t] + bhu[t] + bmo[t]) : 0.f;
      bhead[t] = (t < 20) ? blin[t] : ((t < 70) ? bd1[t - 20] : 0.f);
    }
  } else {
    for (int i = tid; i < zeroCount; i += 256) zeroRegion[i] = 0;
  }
}

// ---------------- stage-1 GEMM (938 blocks, 512 thr = 8 waves, wave 64x64) + adjacency ----------------
// acc[4][4] = 64 AGPR + ~64 VGPR -> 4 waves/SIMD via launch_bounds(512,4).
// A: LDS dbuf [2][64][36] bf16, one f32x4/thread/step, 2-step named-set prefetch.
// B: bb[4] single-buffer from frag-order global (L2). Raw nodrain barriers.
// Blocks >= NGEMM: padded-adjacency scatter (separate esrcP/ewP arrays).
__global__ __launch_bounds__(512, 4) void gemm_stage1_adj(
    const float* __restrict__ Af, const unsigned short* __restrict__ Bf,
    const float* __restrict__ bias, unsigned short* __restrict__ C,
    int M, int Kreal, int ksteps, int NGEMM,
    const int* __restrict__ dst1, const int* __restrict__ src1, const int* __restrict__ eid1,
    int* __restrict__ cnt1, int* __restrict__ esrcP1, float* __restrict__ ewP1, int E1,
    const int* __restrict__ dst2, const int* __restrict__ src2, const int* __restrict__ eid2,
    int* __restrict__ cnt2, int* __restrict__ esrcP2, float* __restrict__ ewP2, int E2,
    const float* __restrict__ wall)
{
  __shared__ unsigned short As[2][64][36];

  if (blockIdx.x >= NGEMM) {
    int e = (blockIdx.x - NGEMM) * 512 + threadIdx.x;
    if (e < E1) {
      int d = dst1[e];
      int pos = atomicAdd(&cnt1[d], 1);
      if (pos < PAD) {
        esrcP1[d * PAD + pos] = src1[e];
        ewP1[d * PAD + pos] = wall[eid1[e]];
      }
    } else if (e < E1 + E2) {
      int e2 = e - E1;
      int d = dst2[e2];
      int pos = atomicAdd(&cnt2[d], 1);
      if (pos < PAD) {
        esrcP2[d * PAD + pos] = src2[e2];
        ewP2[d * PAD + pos] = wall[eid2[e2]];
      }
    }
    return;
  }

  const int tid = threadIdx.x;
  const int lane = tid & 63;
  const int wv = tid >> 6;            // 0..7
  const int rowBase = blockIdx.x * 64;
  const int sRow = tid >> 3;          // 0..63
  const int sC = (tid & 7) << 2;      // 0,4,...,28
  const int aRow = rowBase + sRow;
  const bool aOK = aRow < M;
  const int fr = lane & 15;
  const int fq = lane >> 4;

  const unsigned short* bWave = Bf + ((size_t)(wv * 4) * 64 + lane) * 8;

  f32x4 acc[4][4] = {};
  f32x4 a0, a1;                   // named A staging sets
  bf16x8 bb[4];

  auto loadB = [&](int t) {
    const unsigned short* bp = bWave + (size_t)t * 16384;
    #pragma unroll
    for (int ni = 0; ni < 4; ++ni) bb[ni] = *(const bf16x8*)(bp + ni * 512);
  };
  auto loadA0 = [&](int t) {
    const int k0 = t * 32 + sC;
    if (aOK && (k0 + 4) <= Kreal) a0 = *(const f32x4*)(Af + (size_t)aRow * Kreal + k0);
    else { a0[0]=0.f; a0[1]=0.f; a0[2]=0.f; a0[3]=0.f; }
  };
  auto loadA1 = [&](int t) {
    const int k0 = t * 32 + sC;
    if (aOK && (k0 + 4) <= Kreal) a1 = *(const f32x4*)(Af + (size_t)aRow * Kreal + k0);
    else { a1[0]=0.f; a1[1]=0.f; a1[2]=0.f; a1[3]=0.f; }
  };
  auto writeA0 = [&](int buf) {
    usv4 w;
    w[0]=f2bf(a0[0]); w[1]=f2bf(a0[1]); w[2]=f2bf(a0[2]); w[3]=f2bf(a0[3]);
    *(usv4*)&As[buf][sRow][sC] = w;
  };
  auto writeA1 = [&](int buf) {
    usv4 w;
    w[0]=f2bf(a1[0]); w[1]=f2bf(a1[1]); w[2]=f2bf(a1[2]); w[3]=f2bf(a1[3]);
    *(usv4*)&As[buf][sRow][sC] = w;
  };
  auto compute = [&](int buf) {
    bf16x8 af[4];
    #pragma unroll
    for (int mi = 0; mi < 4; ++mi)
      af[mi] = *(const bf16x8*)&As[buf][(mi << 4) + fr][fq << 3];
    #pragma unroll
    for (int ni = 0; ni < 4; ++ni)
      #pragma unroll
      for (int mi = 0; mi < 4; ++mi)
        acc[mi][ni] = __builtin_amdgcn_mfma_f32_16x16x32_bf16(af[mi], bb[ni], acc[mi][ni], 0, 0, 0);
  };

  const int ksm1 = ksteps - 1;
  loadA0(0);
  loadB(0);
  loadA1(1 < ksm1 ? 1 : ksm1);
  writeA0(0);
  barrier_nodrain();
  loadA0(2 < ksm1 ? 2 : ksm1);

  for (int t = 0; t + 1 < ksteps; t += 2) {
    compute(0);
    loadB(t + 1);
    writeA1(1);
    barrier_nodrain();
    loadA1(t + 3 < ksm1 ? t + 3 : ksm1);
    compute(1);
    loadB(t + 2 < ksm1 ? t + 2 : ksm1);
    writeA0(0);
    barrier_nodrain();
    loadA0(t + 4 < ksm1 ? t + 4 : ksm1);
  }
  compute(0);   // tail (ksteps odd)

  #pragma unroll
  for (int mi = 0; mi < 4; ++mi) {
    const int row0 = rowBase + (mi << 4) + (fq << 2);
    #pragma unroll
    for (int ni = 0; ni < 4; ++ni) {
      const int col = (wv << 6) + (ni << 4) + fr;
      if (col < 416) {
        const float bv = (col < 400) ? bias[col] : 0.f;
        #pragma unroll
        for (int r = 0; r < 4; ++r) {
          const int row = row0 + r;
          if (row < M) C[(size_t)row * 416 + col] =
              (col < 400) ? f2bf(acc[mi][ni][r] + bv) : (unsigned short)0;
        }
      }
    }
  }
}

// ---------------- fused GNN layer: gather (padded adj) -> LDS -> GEMM (-> head + bn) ----------------
template<int HEAD, int ROWS>
__global__ __launch_bounds__(512) void fused_layer(
    const unsigned short* __restrict__ hsrc, const int* __restrict__ deg,
    const int* __restrict__ esrcP, const float* __restrict__ ewP,
    const unsigned short* __restrict__ Bf, const float* __restrict__ bias,
    unsigned short* __restrict__ Cout,
    const unsigned short* __restrict__ BfH, const float* __restrict__ biasH,
    float* __restrict__ outHx, float* __restrict__ dRaw, float* __restrict__ stats, int nDst)
{
  constexpr int MI = ROWS / 16;
  constexpr int NPW = ROWS / 8;        // nodes per wave
  __shared__ unsigned short T[ROWS][456];
  const int tid = threadIdx.x;
  const int lane = tid & 63;
  const int wv = tid >> 6;
  const int rowBase = blockIdx.x * ROWS;
  const int fr = lane & 15;
  const int fq = lane >> 4;

  for (int i = 0; i < NPW; ++i) {
    const int row = wv * NPW + i;
    const int node = rowBase + row;
    if (lane < 52) {
      float a[8];
      if (node < nDst) {
        ushort8 v = *(const ushort8*)(hsrc + (size_t)node * 416 + lane * 8);
        #pragma unroll
        for (int j = 0; j < 8; ++j) a[j] = bf2f(v[j]);
        int dg = deg[node]; if (dg > PAD) dg = PAD;
        const int e0 = node * PAD, e1 = e0 + dg;
        int e = e0;
        for (; e + 16 <= e1; e += 16) {
          int ss[16]; float ww[16];
          #pragma unroll
          for (int u = 0; u < 16; ++u) { ss[u] = esrcP[e + u]; ww[u] = ewP[e + u]; }
          ushort8 q0  = *(const ushort8*)(hsrc + (size_t)ss[0]  * 416 + lane * 8);
          ushort8 q1  = *(const ushort8*)(hsrc + (size_t)ss[1]  * 416 + lane * 8);
          ushort8 q2  = *(const ushort8*)(hsrc + (size_t)ss[2]  * 416 + lane * 8);
          ushort8 q3  = *(const ushort8*)(hsrc + (size_t)ss[3]  * 416 + lane * 8);
          ushort8 q4  = *(const ushort8*)(hsrc + (size_t)ss[4]  * 416 + lane * 8);
          ushort8 q5  = *(const ushort8*)(hsrc + (size_t)ss[5]  * 416 + lane * 8);
          ushort8 q6  = *(const ushort8*)(hsrc + (size_t)ss[6]  * 416 + lane * 8);
          ushort8 q7  = *(const ushort8*)(hsrc + (size_t)ss[7]  * 416 + lane * 8);
          ushort8 q8  = *(const ushort8*)(hsrc + (size_t)ss[8]  * 416 + lane * 8);
          ushort8 q9  = *(const ushort8*)(hsrc + (size_t)ss[9]  * 416 + lane * 8);
          ushort8 q10 = *(const ushort8*)(hsrc + (size_t)ss[10] * 416 + lane * 8);
          ushort8 q11 = *(const ushort8*)(hsrc + (size_t)ss[11] * 416 + lane * 8);
          ushort8 q12 = *(const ushort8*)(hsrc + (size_t)ss[12] * 416 + lane * 8);
          ushort8 q13 = *(const ushort8*)(hsrc + (size_t)ss[13] * 416 + lane * 8);
          ushort8 q14 = *(const ushort8*)(hsrc + (size_t)ss[14] * 416 + lane * 8);
          ushort8 q15 = *(const ushort8*)(hsrc + (size_t)ss[15] * 416 + lane * 8);
          #pragma unroll
          for (int j = 0; j < 8; ++j) {
            float p0 = (bf2f(q0[j])*ww[0] + bf2f(q1[j])*ww[1]) + (bf2f(q2[j])*ww[2] + bf2f(q3[j])*ww[3]);
            float p1 = (bf2f(q4[j])*ww[4] + bf2f(q5[j])*ww[5]) + (bf2f(q6[j])*ww[6] + bf2f(q7[j])*ww[7]);
            float p2 = (bf2f(q8[j])*ww[8] + bf2f(q9[j])*ww[9]) + (bf2f(q10[j])*ww[10] + bf2f(q11[j])*ww[11]);
            float p3 = (bf2f(q12[j])*ww[12] + bf2f(q13[j])*ww[13]) + (bf2f(q14[j])*ww[14] + bf2f(q15[j])*ww[15]);
            a[j] += (p0 + p1) + (p2 + p3);
          }
        }
        for (; e + 4 <= e1; e += 4) {
          const int s0 = esrcP[e], s1 = esrcP[e+1], s2 = esrcP[e+2], s3 = esrcP[e+3];
          const float w0 = ewP[e], w1 = ewP[e+1], w2 = ewP[e+2], w3 = ewP[e+3];
          ushort8 q0 = *(const ushort8*)(hsrc + (size_t)s0 * 416 + lane * 8);
          ushort8 q1 = *(const ushort8*)(hsrc + (size_t)s1 * 416 + lane * 8);
          ushort8 q2 = *(const ushort8*)(hsrc + (size_t)s2 * 416 + lane * 8);
          ushort8 q3 = *(const ushort8*)(hsrc + (size_t)s3 * 416 + lane * 8);
          #pragma unroll
          for (int j = 0; j < 8; ++j)
            a[j] += (bf2f(q0[j]) * w0 + bf2f(q1[j]) * w1) + (bf2f(q2[j]) * w2 + bf2f(q3[j]) * w3);
        }
        for (; e < e1; ++e) {
          const int s = esrcP[e];
          const float w = ewP[e];
          ushort8 q = *(const ushort8*)(hsrc + (size_t)s * 416 + lane * 8);
          #pragma unroll
          for (int j = 0; j < 8; ++j) a[j] += bf2f(q[j]) * w;
        }
        const float inv = 1.f / ((float)dg + 1.f);
        ushort8 o;
        #pragma unroll
        for (int j = 0; j < 8; ++j) o[j] = f2bf(a[j] * inv);
        *(ushort8*)&T[row][lane * 8] = o;
      } else {
        ushort8 o;
        #pragma unroll
        for (int j = 0; j < 8; ++j) o[j] = 0;
        *(ushort8*)&T[row][lane * 8] = o;
      }
    } else if (lane < 57) {
      ushort8 o;
      #pragma unroll
      for (int j = 0; j < 8; ++j) o[j] = 0;
      *(ushort8*)&T[row][416 + (lane - 52) * 8] = o;
    }
  }
  __syncthreads();

  const unsigned short* bWave = Bf + ((size_t)(wv * 4) * 64 + lane) * 8;
  f32x4 acc[MI][4] = {};
  bf16x8 bbA[4], bbB[4];

  auto loadBA = [&](int kh) {
    const unsigned short* bp = bWave + (size_t)kh * 16384;
    #pragma unroll
    for (int ni = 0; ni < 4; ++ni) bbA[ni] = *(const bf16x8*)(bp + ni * 512);
  };
  auto loadBB = [&](int kh) {
    const unsigned short* bp = bWave + (size_t)kh * 16384;
    #pragma unroll
    for (int ni = 0; ni < 4; ++ni) bbB[ni] = *(const bf16x8*)(bp + ni * 512);
  };
  auto computeA2 = [&](int kh) {
    bf16x8 af[MI];
    #pragma unroll
    for (int mi = 0; mi < MI; ++mi)
      af[mi] = *(const bf16x8*)&T[(mi << 4) + fr][kh * 32 + (fq << 3)];
    #pragma unroll
    for (int ni = 0; ni < 4; ++ni)
      #pragma unroll
      for (int mi = 0; mi < MI; ++mi)
        acc[mi][ni] = __builtin_amdgcn_mfma_f32_16x16x32_bf16(af[mi], bbA[ni], acc[mi][ni], 0, 0, 0);
  };
  auto computeB2 = [&](int kh) {
    bf16x8 af[MI];
    #pragma unroll
    for (int mi = 0; mi < MI; ++mi)
      af[mi] = *(const bf16x8*)&T[(mi << 4) + fr][kh * 32 + (fq << 3)];
    #pragma unroll
    for (int ni = 0; ni < 4; ++ni)
      #pragma unroll
      for (int mi = 0; mi < MI; ++mi)
        acc[mi][ni] = __builtin_amdgcn_mfma_f32_16x16x32_bf16(af[mi], bbB[ni], acc[mi][ni], 0, 0, 0);
  };

  loadBA(0);
  loadBB(1);
  for (int kh = 0; kh + 1 < 14; kh += 2) {
    computeA2(kh);
    loadBA(kh + 2 < 13 ? kh + 2 : 13);
    computeB2(kh + 1);
    loadBB(kh + 3 < 13 ? kh + 3 : 13);
  }

  if (HEAD == 0) {
    #pragma unroll
    for (int mi = 0; mi < MI; ++mi) {
      const int row0 = rowBase + (mi << 4) + (fq << 2);
      #pragma unroll
      for (int ni = 0; ni < 4; ++ni) {
        const int col = (wv << 6) + (ni << 4) + fr;
        if (col < 416) {
          const float bv = (col < 400) ? bias[col] : 0.f;
          #pragma unroll
          for (int r = 0; r < 4; ++r) {
            const int row = row0 + r;
            if (row < nDst) Cout[(size_t)row * 416 + col] =
                (col < 400) ? f2bf(acc[mi][ni][r] + bv) : (unsigned short)0;
          }
        }
      }
    }
  } else {
    __syncthreads();
    #pragma unroll
    for (int mi = 0; mi < MI; ++mi) {
      const int lrow0 = (mi << 4) + (fq << 2);
      #pragma unroll
      for (int ni = 0; ni < 4; ++ni) {
        const int col = (wv << 6) + (ni << 4) + fr;
        if (col < 456) {
          const float bv = (col < 400) ? bias[col] : 0.f;
          #pragma unroll
          for (int r = 0; r < 4; ++r)
            T[lrow0 + r][col] = (col < 400) ? f2bf(acc[mi][ni][r] + bv) : (unsigned short)0;
        }
      }
    }
    __syncthreads();
    const unsigned short* bhWave = BfH + ((size_t)wv * 64 + lane) * 8;
    f32x4 acc2[MI] = {};
    bf16x8 bhA, bhB;
    auto loadHA = [&](int kh) { bhA = *(const bf16x8*)(bhWave + (size_t)kh * 16384); };
    auto loadHB = [&](int kh) { bhB = *(const bf16x8*)(bhWave + (size_t)kh * 16384); };
    auto computeHA = [&](int kh) {
      #pragma unroll
      for (int mi = 0; mi < MI; ++mi) {
        bf16x8 af = *(const bf16x8*)&T[(mi << 4) + fr][kh * 32 + (fq << 3)];
        acc2[mi] = __builtin_amdgcn_mfma_f32_16x16x32_bf16(af, bhA, acc2[mi], 0, 0, 0);
      }
    };
    auto computeHB = [&](int kh) {
      #pragma unroll
      for (int mi = 0; mi < MI; ++mi) {
        bf16x8 af = *(const bf16x8*)&T[(mi << 4) + fr][kh * 32 + (fq << 3)];
        acc2[mi] = __builtin_amdgcn_mfma_f32_16x16x32_bf16(af, bhB, acc2[mi], 0, 0, 0);
      }
    };
    loadHA(0);
    loadHB(1);
    for (int kh = 0; kh + 1 < 14; kh += 2) {
      computeHA(kh);
      loadHA(kh + 2 < 13 ? kh + 2 : 13);
      computeHB(kh + 1);
      loadHB(kh + 3 < 13 ? kh + 3 : 13);
    }
    const int col = (wv << 4) + fr;
    const bool colOK = (col < 70);
    const float bv = colOK ? biasH[col] : 0.f;
    if (colOK) {
      #pragma unroll
      for (int mi = 0; mi < MI; ++mi) {
        const int row0 = rowBase + (mi << 4) + (fq << 2);
        #pragma unroll
        for (int r = 0; r < 4; ++r) {
          const int row = row0 + r;
          if (row < nDst) {
            float v = acc2[mi][r] + bv;
            if (col < 20) outHx[(size_t)row * 20 + col] = v;
            else          dRaw[(size_t)row * 50 + (col - 20)] = v;
          }
        }
      }
    }
    float s = 0.f, s2 = 0.f;
    if (col >= 20 && col < 70) {
      #pragma unroll
      for (int mi = 0; mi < MI; ++mi) {
        const int row0 = rowBase + (mi << 4) + (fq << 2);
        #pragma unroll
        for (int r = 0; r < 4; ++r) {
          if (row0 + r < nDst) {
            float v = acc2[mi][r] + bv;
            s += v; s2 += v * v;
          }
        }
      }
    }
    s  += __shfl_xor(s, 16);  s  += __shfl_xor(s, 32);
    s2 += __shfl_xor(s2, 16); s2 += __shfl_xor(s2, 32);
    if (col >= 20 && col < 70 && fq == 0) {
      atomicAdd(&stats[col - 20], s);
      atomicAdd(&stats[50 + col - 20], s2);
    }
  }
}

// ---------------- bn finalize + domain head ----------------
__global__ void domain_head2(const float* __restrict__ d, const float* __restrict__ stats,
                             const float* __restrict__ gamma, const float* __restrict__ beta,
                             const float* __restrict__ Wd2, const float* __restrict__ bd2,
                             float* __restrict__ out, int rows)
{
  __shared__ float ss[100];
  const int t = threadIdx.x;
  if (t < 50) {
    float mu = stats[t] / rows;
    float var = stats[50 + t] / rows - mu * mu;
    float inv = rsqrtf(var + 1e-5f);
    float sc = gamma[t] * inv;
    ss[t] = sc;
    ss[50 + t] = beta[t] - mu * sc;
  }
  __syncthreads();
  int r = blockIdx.x * 256 + t;
  if (r >= rows) return;
  float o0 = bd2[0], o1 = bd2[1];
  const float* dr = d + (size_t)r * 50;
  #pragma unroll 10
  for (int c = 0; c < 50; ++c) {
    float v = dr[c] * ss[c] + ss[50 + c];
    v = fmaxf(v, 0.f);
    o0 += v * Wd2[c];
    o1 += v * Wd2[50 + c];
  }
  out[r * 2]     = o0;
  out[r * 2 + 1] = o1;
}

// ---------------- launch ----------------
extern "C" void kernel_launch(void* const* d_in, const int* in_sizes, int n_in,
                              void* d_out, int out_size, void* d_ws, size_t ws_size,
                              hipStream_t stream)
{
  const float* x    = (const float*)d_in[0];
  const float* wall = (const float*)d_in[1];
  const float* Wsh  = (const float*)d_in[2];
  const float* bsh  = (const float*)d_in[3];
  const float* Whu  = (const float*)d_in[4];
  const float* bhu  = (const float*)d_in[5];
  const float* Wmo  = (const float*)d_in[6];
  const float* bmo  = (const float*)d_in[7];
  const float* Wn1  = (const float*)d_in[8];
  const float* bn1  = (const float*)d_in[9];
  const float* Wn2  = (const float*)d_in[10];
  const float* bn2  = (const float*)d_in[11];
  const float* Wlin = (const float*)d_in[12];
  const float* blin = (const float*)d_in[13];
  const float* Wd1  = (const float*)d_in[14];
  const float* bd1  = (const float*)d_in[15];
  const float* gamma= (const float*)d_in[16];
  const float* beta = (const float*)d_in[17];
  const float* Wd2  = (const float*)d_in[18];
  const float* bd2  = (const float*)d_in[19];
  const int* src1 = (const int*)d_in[20];
  const int* dst1 = (const int*)d_in[21];
  const int* eid1 = (const int*)d_in[22];
  const int* src2 = (const int*)d_in[23];
  const int* dst2 = (const int*)d_in[24];
  const int* eid2 = (const int*)d_in[25];

  char* ws = (char*)d_ws;
  unsigned short* h    = (unsigned short*)(ws);                    // [60000][416] bf16
  unsigned short* h1   = (unsigned short*)(ws + 49920000ULL);      // [30000][416]
  float* d_raw         = (float*)(ws + 74880000ULL);               // [15000][50] f32
  unsigned short* WCf  = (unsigned short*)(ws + 77880000ULL);      // 64*16384 ushorts
  unsigned short* WN1f = (unsigned short*)(ws + 79977152ULL);      // 14*16384
  unsigned short* WN2f = (unsigned short*)(ws + 80435904ULL);
  unsigned short* WHf  = (unsigned short*)(ws + 80894656ULL);
  float* b3      = (float*)(ws + 81353408ULL);
  float* bhead   = (float*)(ws + 81355456ULL);
  // contiguous zero region: cnt1, cnt2, stats (45100 ints)
  int*   cnt1    = (int*)(ws + 81357504ULL);                       // 120000 B
  int*   cnt2    = (int*)(ws + 81477504ULL);                       // 60000 B
  float* stats   = (float*)(ws + 81537504ULL);                     // 400 B
  int*   esrcP1  = (int*)(ws + 81538304ULL);                       // 11520000 B
  float* ewP1    = (float*)(ws + 93058304ULL);                     // 11520000 B
  int*   esrcP2  = (int*)(ws + 104578304ULL);                      // 5760000 B
  float* ewP2    = (float*)(ws + 110338304ULL);                    // 5760000 B

  const int E1 = 960000, E2 = 480000;
  const int N0 = 60000, N1 = 30000, N2 = 15000;

  prep_frag<<<6786, 256, 0, stream>>>(
      Wsh, Whu, Wmo, Wn1, Wn2, Wlin, Wd1, WCf, WN1f, WN2f, WHf,
      bsh, bhu, bmo, blin, bd1, b3, bhead,
      cnt1, 45100);

  gemm_stage1_adj<<<938 + 2813, 512, 0, stream>>>(
      x, WCf, b3, h, N0, 2000, 63, 938,
      dst1, src1, eid1, cnt1, esrcP1, ewP1, E1,
      dst2, src2, eid2, cnt2, esrcP2, ewP2, E2, wall);

  float* out_hx  = (float*)d_out;            // 15000 x 20
  float* out_dom = (float*)d_out + 300000;   // 15000 x 2

  fused_layer<0, 32><<<(N1 + 31) / 32, 512, 0, stream>>>(
      h, cnt1, esrcP1, ewP1, WN1f, bn1, h1, nullptr, nullptr, nullptr, nullptr, nullptr, N1);

  fused_layer<1, 32><<<(N2 + 31) / 32, 512, 0, stream>>>(
      h1, cnt2, esrcP2, ewP2, WN2f, bn2, nullptr, WHf, bhead, out_hx, d_raw, stats, N2);

  domain_head2<<<(N2 + 255) / 256, 256, 0, stream>>>(d_raw, stats, gamma, beta, Wd2, bd2, out_dom, N2);
}